// Round 4
// baseline (277.414 us; speedup 1.0000x reference)
//
#include <hip/hip_runtime.h>
#include <math.h>

// Problem constants: T=512, E=64, H=2*E=128, batch derived at launch.
#define TT 512
#define EE 64
#define HH 128
#define NBLK_U 1536                 // upper-triangle streaming blocks
#define UCNT (TT * (TT - 1) / 2)    // 130816 strict-upper pairs per batch

// # strict-upper elements in rows < i (row-major (i,j>i) enumeration)
__device__ __forceinline__ int tri_off(int i) {
    return (TT - 1) * i - (i * (i - 1)) / 2;
}

// Fused kernel. Key structural fact: tril(i-j) sends the ENTIRE strict upper
// triangle (half the 268 MB output) to rows[0]; the lower triangle is
// d-homogeneous along diagonals. Every block computes its single needed row
// via a tiny L2-hot GEMV (W1+W2 = 96 KB) and then pure-streams its output
// chunk — no producer kernel, no inter-kernel dependency.
//   blocks [0,512):          L-block, d = blockIdx.x: writes (bb, j+d, j) rows
//   blocks [512,512+NBLK_U): U-block: writes a strided chunk of strict-upper rows
__global__ __launch_bounds__(256) void fused_kernel(
        const float* __restrict__ pos,
        const float* __restrict__ W1,
        const float* __restrict__ b1,
        const float* __restrict__ W2,
        const float* __restrict__ b2,
        float4* __restrict__ out4,
        int bN) {
    const int t = threadIdx.x;       // 0..255
    const int c = t & (HH - 1);      // output column 0..127
    const int s = t >> 7;            // K-slice 0..1 (wave-uniform)

    const bool is_lower = (blockIdx.x < TT);
    const int d = is_lower ? blockIdx.x : 0;

    __shared__ float p[EE];          // pos_table row d
    __shared__ float part[2][HH];    // K-slice partials
    __shared__ float hs[HH];         // hidden activations
    __shared__ float row_s[HH];      // final row

    // ---- GEMV: row_s = gelu_exact(pos[d] @ W1 + b1) @ W2 + b2 ----
    if (t < EE) p[t] = pos[d * EE + t];
    __syncthreads();

    float acc = (s == 0) ? b1[c] : 0.0f;
    {
        const int e0 = s * (EE / 2);
#pragma unroll 8
        for (int e = 0; e < EE / 2; ++e)
            acc += p[e0 + e] * W1[(e0 + e) * HH + c];   // coalesced across c
    }
    part[s][c] = acc;
    __syncthreads();

    if (s == 0) {
        float hv = part[0][c] + part[1][c];
        hs[c] = 0.5f * hv * (1.0f + erff(hv * 0.7071067811865475f));
    }
    __syncthreads();

    float acc2 = (s == 0) ? b2[c] : 0.0f;
    {
        const int k0 = s * (HH / 2);
#pragma unroll 8
        for (int k = 0; k < HH / 2; ++k)
            acc2 += hs[k0 + k] * W2[(k0 + k) * HH + c];
    }
    part[s][c] = acc2;
    __syncthreads();
    if (s == 0) row_s[c] = part[0][c] + part[1][c];
    __syncthreads();

    // ---- Stream the row to all of this block's output locations ----
    // 32 lanes x float4 = one 512 B contiguous row per half-wave (proven
    // round-0 full-line store pattern, ~6.2 TB/s).
    const int q  = t & 31;           // float4 index within row (HH/4 = 32)
    const int rl = t >> 5;           // row slot 0..7 (8 rows per pass)
    const float4 v = reinterpret_cast<const float4*>(row_s)[q];

    if (is_lower) {
        const int n = TT - d;        // rows per batch on this diagonal
        for (int bb = 0; bb < bN; ++bb) {
            const long base_b = (long)bb * TT * TT;
            for (int j = rl; j < n; j += 8) {
                const long r = base_b + (long)(j + d) * TT + j;
                out4[r * (HH / 4) + q] = v;
            }
        }
    } else {
        const int  e   = blockIdx.x - TT;
        const long NUP = (long)bN * UCNT;
        for (long g = (long)e * 8 + rl; g < NUP; g += (long)NBLK_U * 8) {
            int  bb = 0;
            long uu = g;
            while (uu >= UCNT) { uu -= UCNT; ++bb; }   // bN is tiny (2)
            const int ui = (int)uu;
            // decode strict-upper flat index -> (i,j): solve
            // off(i) <= ui < off(i+1), off(i) = 511*i - i*(i-1)/2.
            // 1023^2 - 8*ui is an exact-int fp32 value; sqrt is +-1 ulp,
            // integer fixup makes it exact.
            const float fa = (float)(1023 * 1023 - 8 * ui);
            int i = (int)((1023.0f - sqrtf(fa)) * 0.5f);
            if (i < 0) i = 0;
            if (i > TT - 2) i = TT - 2;
            while (tri_off(i + 1) <= ui) ++i;
            while (i > 0 && tri_off(i) > ui) --i;
            const int j = i + 1 + (ui - tri_off(i));
            const long r = (long)bb * TT * TT + (long)i * TT + j;
            out4[r * (HH / 4) + q] = v;
        }
    }
}

extern "C" void kernel_launch(void* const* d_in, const int* in_sizes, int n_in,
                              void* d_out, int out_size, void* d_ws, size_t ws_size,
                              hipStream_t stream) {
    // setup_inputs order: b(int scalar), pos_table, W1, b1, W2, b2 — all fp32
    const float* pos = (const float*)d_in[1];
    const float* W1  = (const float*)d_in[2];
    const float* b1  = (const float*)d_in[3];
    const float* W2  = (const float*)d_in[4];
    const float* b2  = (const float*)d_in[5];
    float4* out4 = (float4*)d_out;

    // out_size is an ELEMENT count (proven round-0/2: out_size/4 float4s passed
    // verification with full coverage). Byte-units guard kept anyway.
    const bool sizes_in_bytes = (in_sizes[1] == TT * EE * 4);
    const long total_floats   = sizes_in_bytes ? (long)out_size / 4
                                               : (long)out_size;
    int bN = (int)(total_floats / ((long)TT * TT * HH));
    if (bN < 1) bN = 1;

    fused_kernel<<<TT + NBLK_U, 256, 0, stream>>>(pos, W1, b1, W2, b2, out4, bN);
}

// Round 5
// 263.344 us; speedup vs baseline: 1.0534x; 1.0534x over previous
//
#include <hip/hip_runtime.h>
#include <math.h>

// Problem constants (from reference): T=512, E=64, H=2*E=128, b derived at launch.
#define TT 512
#define EE 64
#define HH 128

// Kernel 1: rows[d][h] = (gelu_exact(pos[d] @ W1 + b1) @ W2 + b2)[h]
// One block per distance d (512 blocks), 512 threads: column c = t&127,
// K-slice s = t>>7 (4-way split of the reduction). Measured: a few us —
// the producer is NOT the bottleneck (R2 vs R0 established this).
__global__ __launch_bounds__(512) void rows_kernel(
        const float* __restrict__ pos,
        const float* __restrict__ W1,
        const float* __restrict__ b1,
        const float* __restrict__ W2,
        const float* __restrict__ b2,
        float* __restrict__ rows) {
    const int d = blockIdx.x;
    const int t = threadIdx.x;      // 0..511
    const int c = t & (HH - 1);     // output column 0..127
    const int s = t >> 7;           // K-slice 0..3 (wave-uniform)

    __shared__ float p[EE];         // pos_table row d
    __shared__ float part[4][HH];   // K-slice partial sums
    __shared__ float h[HH];         // hidden activations

    if (t < EE) p[t] = pos[d * EE + t];
    __syncthreads();

    // Phase 1: h = gelu(pos[d] @ W1 + b1); each s-slice sums 16 of 64 terms.
    float acc = (s == 0) ? b1[c] : 0.0f;
    const int e0 = s * (EE / 4);
#pragma unroll
    for (int e = 0; e < EE / 4; ++e)
        acc += p[e0 + e] * W1[(e0 + e) * HH + c];   // coalesced across c
    part[s][c] = acc;
    __syncthreads();

    float hv = part[0][c] + part[1][c] + part[2][c] + part[3][c];
    hv = 0.5f * hv * (1.0f + erff(hv * 0.7071067811865475f));  // exact gelu
    if (s == 0) h[c] = hv;
    __syncthreads();

    // Phase 2: rows[d] = h @ W2 + b2; each s-slice sums 32 of 128 terms.
    float acc2 = (s == 0) ? b2[c] : 0.0f;
    const int k0 = s * (HH / 4);
#pragma unroll
    for (int k = 0; k < HH / 4; ++k)
        acc2 += h[k0 + k] * W2[(k0 + k) * HH + c];  // coalesced across c
    part[s][c] = acc2;
    __syncthreads();

    if (s == 0)
        rows[d * HH + c] = part[0][c] + part[1][c] + part[2][c] + part[3][c];
}

// Kernel 2: out[b][i][j][:] = rows[max(i-j,0)][:]
// One thread per output float4; consecutive lanes write consecutive 16 B ->
// each wave stores 1 KB contiguous, monotone across the whole 268 MB
// (ideal DRAM stream locality — measured 6.13 TB/s, ~95% of the poison
// fill's own rate on this buffer). Reads hit the L2-resident 256 KB rows
// table (FETCH_SIZE ~0.8 MB measured). Do NOT restructure the write order:
// the diagonal/triangular fused variant (R4) measured -13 us from exactly
// that (512-B-granular scattered streams, ~4.7 TB/s).
__global__ void scatter_kernel(const float4* __restrict__ rows4,
                               float4* __restrict__ out4) {
    const long idx = (long)blockIdx.x * blockDim.x + threadIdx.x;
    const int  q = (int)(idx & 31);          // float4 index within row (HH/4=32)
    const long r = idx >> 5;                 // flat (b,i,j) row index
    const int  j = (int)(r & (TT - 1));
    const int  i = (int)((r >> 9) & (TT - 1));
    const int  d = (i >= j) ? (i - j) : 0;   // tril(i-j)
    out4[idx] = rows4[d * (HH / 4) + q];
}

extern "C" void kernel_launch(void* const* d_in, const int* in_sizes, int n_in,
                              void* d_out, int out_size, void* d_ws, size_t ws_size,
                              hipStream_t stream) {
    // setup_inputs order: b(int scalar), pos_table, W1, b1, W2, b2 — all fp32
    const float* pos = (const float*)d_in[1];
    const float* W1  = (const float*)d_in[2];
    const float* b1  = (const float*)d_in[3];
    const float* W2  = (const float*)d_in[4];
    const float* b2  = (const float*)d_in[5];
    float* out  = (float*)d_out;
    float* rows = (float*)d_ws;              // TT*HH*4 = 256 KB scratch

    rows_kernel<<<TT, 512, 0, stream>>>(pos, W1, b1, W2, b2, rows);

    // out_size is an ELEMENT count (proven: rounds 0/2 wrote out_size/4
    // float4s and passed verification with full coverage). Byte-units guard
    // kept anyway — pos_table is 512*64 fp32 = 32768 elements / 131072 bytes.
    const bool sizes_in_bytes = (in_sizes[1] == TT * EE * 4);
    const long total_floats   = sizes_in_bytes ? (long)out_size / 4
                                               : (long)out_size;
    const long total4 = total_floats / 4;
    const int  block  = 256;
    const long grid   = (total4 + block - 1) / block;
    scatter_kernel<<<dim3((unsigned)grid), dim3(block), 0, stream>>>(
        (const float4*)rows, (float4*)out);
}